// Round 1
// baseline (1075.943 us; speedup 1.0000x reference)
//
#include <hip/hip_runtime.h>

#define HDIM 256
#define MTILE 64
#define NITER 4          // row-tiles per block (256 rows/block)
#define APITCH 264       // 256 + 8 pad (shorts)

typedef __attribute__((ext_vector_type(8))) short short8;
typedef __attribute__((ext_vector_type(4))) short short4v;
typedef __attribute__((ext_vector_type(4))) float floatx4;

__device__ __forceinline__ unsigned short f2bf(float f){
  unsigned u = __float_as_uint(f);
  u += 0x7FFFu + ((u>>16)&1u);
  return (unsigned short)(u>>16);
}
__device__ __forceinline__ unsigned fkey(float f){
  unsigned u = __float_as_uint(f);
  return u ^ ((unsigned)((int)u>>31) | 0x80000000u);
}
__device__ __forceinline__ float fdec(unsigned u){
  unsigned b = (u & 0x80000000u) ? (u & 0x7FFFFFFFu) : ~u;
  return __uint_as_float(b);
}

// fused pre-pass: [0,ZB) zero stats | [ZB,ZB+PB) W1->bf16 transpose | rest: segment bounds
__global__ void k_pre(const float* __restrict__ W1, unsigned short* __restrict__ W1T,
                      const int* __restrict__ batch, int* __restrict__ segstart,
                      float* __restrict__ zbuf, int zerowords, int n, int B,
                      int ZB, int PB){
  const int bid = blockIdx.x, t = threadIdx.x;
  if (bid < ZB){
    int i = bid*256 + t;
    if (i < zerowords) zbuf[i] = 0.f;
  } else if (bid < ZB + PB){
    int col = bid - ZB;
    W1T[col*HDIM + t] = f2bf(W1[t*HDIM + col]);
  } else {
    int i = (bid - ZB - PB)*256 + t;
    if (i >= n) return;
    int b = batch[i];
    int prev = (i == 0) ? -1 : batch[i-1];
    if (prev != b) for (int q = prev+1; q <= b; ++q) segstart[q] = i;
    if (i == n-1) for (int q = b+1; q <= B; ++q) segstart[q] = n;
  }
}

// fused main pass: scores (bf16 MFMA) -> e=exp(s) (no max-subtraction: |s|<=16 so
// exp is fp32-safe and the segmax factor cancels in attn/denom) -> mean/max/attn
// pooling with fp32 x re-read (L2-resident: same 64KB tile staged moments earlier).
__launch_bounds__(256)
__global__ void k_main(const float* __restrict__ x,
                       const unsigned short* __restrict__ w1t,
                       const float* __restrict__ b1,
                       const float* __restrict__ w2,
                       const float* __restrict__ b2,
                       const int* __restrict__ batch,
                       float* __restrict__ denom,
                       float* __restrict__ sums,
                       unsigned* __restrict__ maxu,
                       float* __restrict__ attn,
                       int n)
{
  __shared__ unsigned short As[MTILE*APITCH];
  __shared__ float sp[4][MTILE];
  __shared__ float earr[MTILE];
  __shared__ int sbat[MTILE*NITER];
  const int t = threadIdx.x;
  const int wv = t>>6;
  const int lane = t&63;
  const int l15 = lane&15;
  const int quad = lane>>4;
  const long long base = (long long)blockIdx.x * (MTILE*NITER);

  { long long gr = base + t; sbat[t] = (gr < n) ? batch[gr] : -1; }

  // B fragments: wave wv owns cols [wv*64, wv*64+64), all K in registers
  short8 bf[8][4];
  float b1v[4], w2v[4];
  const int cb = wv*64;
  #pragma unroll
  for (int ct=0; ct<4; ++ct){
    int col = cb + ct*16 + l15;
    b1v[ct] = b1[col];
    w2v[ct] = w2[col];
    #pragma unroll
    for (int kc=0; kc<8; ++kc)
      bf[kc][ct] = *(const short8*)(w1t + (size_t)col*HDIM + kc*32 + quad*8);
  }
  const float b2v = b2[0];

  // pooling accumulators: thread t owns column t
  float psum = 0.f, patt = 0.f, pmx = -INFINITY;
  int curb = -1;

  const float4* x4 = (const float4*)x;
  for (int it = 0; it < NITER; ++it){
    const long long node0 = base + (long long)it*MTILE;
    if (node0 >= n) break;

    // stage A tile (64 rows x 256 k) fp32->bf16 into LDS, coalesced
    #pragma unroll
    for (int j=0; j<MTILE/4; ++j){
      int f = j*256 + t;
      int row = f>>6, c4 = f&63;
      long long gr = node0 + row;
      float4 v = make_float4(0.f,0.f,0.f,0.f);
      if (gr < n) v = x4[gr*(HDIM/4) + c4];
      short4v p;
      p.x=(short)f2bf(v.x); p.y=(short)f2bf(v.y); p.z=(short)f2bf(v.z); p.w=(short)f2bf(v.w);
      *(short4v*)(As + row*APITCH + c4*4) = p;
    }
    __syncthreads();                       // S1: As staged

    #pragma unroll 1
    for (int rt=0; rt<MTILE/16; ++rt){
      floatx4 acc[4];
      #pragma unroll
      for (int ct=0;ct<4;++ct) acc[ct] = (floatx4){0.f,0.f,0.f,0.f};
      #pragma unroll
      for (int kc=0; kc<8; ++kc){
        short8 a = *(const short8*)(As + (rt*16 + l15)*APITCH + kc*32 + quad*8);
        #pragma unroll
        for (int ct=0; ct<4; ++ct)
          acc[ct] = __builtin_amdgcn_mfma_f32_16x16x32_bf16(a, bf[kc][ct], acc[ct], 0, 0, 0);
      }
      float part[4] = {0.f,0.f,0.f,0.f};
      #pragma unroll
      for (int ct=0; ct<4; ++ct){
        #pragma unroll
        for (int r=0; r<4; ++r){
          float h = acc[ct][r] + b1v[ct];
          float z = fminf(fmaxf(2.f*h, -30.f), 30.f);
          float e = __expf(z);
          part[r] += __fdividef(e-1.f, e+1.f) * w2v[ct];
        }
      }
      #pragma unroll
      for (int off=8; off>=1; off>>=1){
        #pragma unroll
        for (int r=0;r<4;++r) part[r] += __shfl_xor(part[r], off, 64);
      }
      if (l15==0){
        #pragma unroll
        for (int r=0;r<4;++r) sp[wv][rt*16 + quad*4 + r] = part[r];
      }
    }
    __syncthreads();                       // S2: sp complete

    // wave 0: s -> e = exp(s), stash in earr, reduce segment denominators
    if (t < MTILE){
      long long gr = node0 + t;
      float e = 0.f; int b = -1;
      if (gr < n){
        float sv = sp[0][t]+sp[1][t]+sp[2][t]+sp[3][t] + b2v;
        e = __expf(sv);
        b = sbat[it*MTILE + t];
      }
      earr[t] = e;
      int b0 = __shfl(b, 0, 64);
      if (__all(b == b0)){                 // whole tile in one segment (common)
        float tot = e;
        #pragma unroll
        for (int off=32; off>=1; off>>=1) tot += __shfl_xor(tot, off, 64);
        if (lane==0 && b0 >= 0) atomicAdd(&denom[b0], tot);
      } else if (b >= 0){
        atomicAdd(&denom[b], e);
      }
    }
    __syncthreads();                       // S3: earr ready

    // pooling over this tile's rows; x re-read hits L2 (just staged)
    int rend = (int)((n - node0 < (long long)MTILE) ? (n - node0) : (long long)MTILE);
#define POOLROW(RR)                                                     \
    {                                                                   \
      int b = sbat[it*MTILE + (RR)];                                    \
      if (b != curb){                                                   \
        if (curb >= 0){                                                 \
          size_t o = (size_t)curb*HDIM + t;                             \
          atomicAdd(&sums[o], psum);                                    \
          atomicAdd(&attn[o], patt);                                    \
          atomicMax(&maxu[o], fkey(pmx));                               \
        }                                                               \
        curb = b; psum = 0.f; patt = 0.f; pmx = -INFINITY;              \
      }                                                                 \
      float v = x[(node0 + (RR))*HDIM + t];                             \
      psum += v;                                                        \
      patt = fmaf(v, earr[(RR)], patt);                                 \
      pmx = fmaxf(pmx, v);                                              \
    }
    if (rend == MTILE){
      #pragma unroll 8
      for (int r=0; r<MTILE; ++r) POOLROW(r)
    } else {
      for (int r=0; r<rend; ++r) POOLROW(r)
    }
#undef POOLROW
  }

  if (curb >= 0){
    size_t o = (size_t)curb*HDIM + t;
    atomicAdd(&sums[o], psum);
    atomicAdd(&attn[o], patt);
    atomicMax(&maxu[o], fkey(pmx));
  }
}

__global__ void k_fin(const float* __restrict__ sums, const unsigned* __restrict__ maxu,
                      const float* __restrict__ attn, const float* __restrict__ denom,
                      const int* __restrict__ segstart,
                      float* __restrict__ out, int bcount){
  int idx = blockIdx.x*256 + threadIdx.x;
  int total = bcount*3*HDIM;
  if (idx >= total) return;
  int b = idx / (3*HDIM);
  int c = idx - b*(3*HDIM);
  int cnt = segstart[b+1] - segstart[b];
  float v;
  if (c < HDIM)        v = sums[(size_t)b*HDIM + c] / fmaxf((float)cnt, 1.f);
  else if (c < 2*HDIM) v = (cnt > 0) ? fdec(maxu[(size_t)b*HDIM + (c-HDIM)]) : 0.f;
  else                 v = attn[(size_t)b*HDIM + (c-2*HDIM)] / fmaxf(denom[b], 1e-30f);
  out[idx] = v;
}

extern "C" void kernel_launch(void* const* d_in, const int* in_sizes, int n_in,
                              void* d_out, int out_size, void* d_ws, size_t ws_size,
                              hipStream_t stream){
  const float* x   = (const float*)d_in[0];
  const int* batch = (const int*)d_in[1];
  const float* W1  = (const float*)d_in[2];
  const float* b1  = (const float*)d_in[3];
  const float* W2  = (const float*)d_in[4];
  const float* b2  = (const float*)d_in[5];
  float* out = (float*)d_out;
  const int n = in_sizes[1];
  const int B = out_size / (3*HDIM);

  char* w = (char*)d_ws;
  unsigned short* W1T = (unsigned short*)w;
  size_t off = (size_t)HDIM*HDIM*2;
  int* segstart = (int*)(w + off);
  off += (size_t)((B+4)&~3)*4;
  float* stats = (float*)(w + off);
  float* denom  = stats;                                   // [B]
  float* sums   = stats + B;                               // [B,H]
  unsigned* maxu = (unsigned*)(stats + B + (size_t)B*HDIM);// [B,H]
  float* attn   = stats + B + 2*(size_t)B*HDIM;            // [B,H]
  int zerowords = B + 3*B*HDIM;

  int ZB  = (zerowords + 255)/256;
  int PB  = HDIM;
  int NBB = (n + 255)/256;
  hipLaunchKernelGGL(k_pre, dim3(ZB + PB + NBB), dim3(256), 0, stream,
                     W1, W1T, batch, segstart, stats, zerowords, n, B, ZB, PB);
  hipLaunchKernelGGL(k_main, dim3((n + MTILE*NITER - 1)/(MTILE*NITER)), dim3(256), 0, stream,
                     x, W1T, b1, W2, b2, batch, denom, sums, maxu, attn, n);
  hipLaunchKernelGGL(k_fin, dim3((out_size + 255)/256), dim3(256), 0, stream,
                     sums, maxu, attn, denom, segstart, out, B);
}

// Round 2
// 1056.227 us; speedup vs baseline: 1.0187x; 1.0187x over previous
//
#include <hip/hip_runtime.h>

#define HDIM 256
#define MTILE 64
#define NITER 4          // row-tiles per block (256 rows/block)
#define APITCH 264       // 256 + 8 pad (shorts)

typedef __attribute__((ext_vector_type(8))) short short8;
typedef __attribute__((ext_vector_type(4))) short short4v;
typedef __attribute__((ext_vector_type(4))) float floatx4;

__device__ __forceinline__ unsigned short f2bf(float f){
  unsigned u = __float_as_uint(f);
  u += 0x7FFFu + ((u>>16)&1u);
  return (unsigned short)(u>>16);
}
__device__ __forceinline__ unsigned fkey(float f){
  unsigned u = __float_as_uint(f);
  return u ^ ((unsigned)((int)u>>31) | 0x80000000u);
}
__device__ __forceinline__ float fdec(unsigned u){
  unsigned b = (u & 0x80000000u) ? (u & 0x7FFFFFFFu) : ~u;
  return __uint_as_float(b);
}

// fused pre-pass: [0,ZB) zero stats | [ZB,ZB+PB) W1->bf16 transpose | rest: segment bounds
__global__ void k_pre(const float* __restrict__ W1, unsigned short* __restrict__ W1T,
                      const int* __restrict__ batch, int* __restrict__ segstart,
                      float* __restrict__ zbuf, int zerowords, int n, int B,
                      int ZB, int PB){
  const int bid = blockIdx.x, t = threadIdx.x;
  if (bid < ZB){
    int i = bid*256 + t;
    if (i < zerowords) zbuf[i] = 0.f;
  } else if (bid < ZB + PB){
    int col = bid - ZB;
    W1T[col*HDIM + t] = f2bf(W1[t*HDIM + col]);
  } else {
    int i = (bid - ZB - PB)*256 + t;
    if (i >= n) return;
    int b = batch[i];
    int prev = (i == 0) ? -1 : batch[i-1];
    if (prev != b) for (int q = prev+1; q <= b; ++q) segstart[q] = i;
    if (i == n-1) for (int q = b+1; q <= B; ++q) segstart[q] = n;
  }
}

// fused main pass: scores (bf16 MFMA) -> e=exp(s) (no max-subtraction: |s|<=16 so
// exp is fp32-safe and the segmax factor cancels in attn/denom) -> mean/max/attn
// pooling. Pool phase: wave w owns rows [w*16,w*16+16) of each tile, lane owns 4
// columns (float4). 16 branchless independent loads when chunk is segment-uniform
// (MLP=16 — the per-row boundary branch in the previous version serialized every
// load behind a potential atomic and was the 575us regression).
__launch_bounds__(256)
__global__ void k_main(const float* __restrict__ x,
                       const unsigned short* __restrict__ w1t,
                       const float* __restrict__ b1,
                       const float* __restrict__ w2,
                       const float* __restrict__ b2,
                       const int* __restrict__ batch,
                       float* __restrict__ denom,
                       float* __restrict__ sums,
                       unsigned* __restrict__ maxu,
                       float* __restrict__ attn,
                       int n)
{
  __shared__ unsigned short As[MTILE*APITCH];
  __shared__ float sp[4][MTILE];
  __shared__ int sbat[MTILE*NITER];
  const int t = threadIdx.x;
  const int wv = t>>6;
  const int lane = t&63;
  const int l15 = lane&15;
  const int quad = lane>>4;
  const long long base = (long long)blockIdx.x * (MTILE*NITER);

  { long long gr = base + t; sbat[t] = (gr < n) ? batch[gr] : -1; }

  // B fragments: wave wv owns cols [wv*64, wv*64+64), all K in registers
  short8 bf[8][4];
  float b1v[4], w2v[4];
  const int cb = wv*64;
  #pragma unroll
  for (int ct=0; ct<4; ++ct){
    int col = cb + ct*16 + l15;
    b1v[ct] = b1[col];
    w2v[ct] = w2[col];
    #pragma unroll
    for (int kc=0; kc<8; ++kc)
      bf[kc][ct] = *(const short8*)(w1t + (size_t)col*HDIM + kc*32 + quad*8);
  }
  const float b2v = b2[0];

  // pooling accumulators: lane owns columns [4*lane, 4*lane+4)
  float4 psum = make_float4(0.f,0.f,0.f,0.f);
  float4 patt = make_float4(0.f,0.f,0.f,0.f);
  float4 pmx  = make_float4(-INFINITY,-INFINITY,-INFINITY,-INFINITY);
  int curb = -1;
  const int rb = wv*16;            // this wave's row base within a tile

#define FLUSH()                                                         \
  {                                                                     \
    size_t o = (size_t)curb*HDIM + 4*lane;                              \
    atomicAdd(&sums[o+0], psum.x); atomicAdd(&sums[o+1], psum.y);       \
    atomicAdd(&sums[o+2], psum.z); atomicAdd(&sums[o+3], psum.w);       \
    atomicAdd(&attn[o+0], patt.x); atomicAdd(&attn[o+1], patt.y);       \
    atomicAdd(&attn[o+2], patt.z); atomicAdd(&attn[o+3], patt.w);       \
    atomicMax(&maxu[o+0], fkey(pmx.x)); atomicMax(&maxu[o+1], fkey(pmx.y)); \
    atomicMax(&maxu[o+2], fkey(pmx.z)); atomicMax(&maxu[o+3], fkey(pmx.w)); \
  }
#define ACCROW(GR, WT)                                                  \
  {                                                                     \
    float4 v = x4[(GR)*(HDIM/4) + lane];                                \
    float ww = (WT);                                                    \
    psum.x += v.x; psum.y += v.y; psum.z += v.z; psum.w += v.w;         \
    patt.x = fmaf(v.x, ww, patt.x); patt.y = fmaf(v.y, ww, patt.y);     \
    patt.z = fmaf(v.z, ww, patt.z); patt.w = fmaf(v.w, ww, patt.w);     \
    pmx.x = fmaxf(pmx.x, v.x); pmx.y = fmaxf(pmx.y, v.y);               \
    pmx.z = fmaxf(pmx.z, v.z); pmx.w = fmaxf(pmx.w, v.w);               \
  }

  const float4* x4 = (const float4*)x;
  for (int it = 0; it < NITER; ++it){
    const long long node0 = base + (long long)it*MTILE;
    if (node0 >= n) break;

    // stage A tile (64 rows x 256 k) fp32->bf16 into LDS, coalesced
    #pragma unroll
    for (int j=0; j<MTILE/4; ++j){
      int f = j*256 + t;
      int row = f>>6, c4 = f&63;
      long long gr = node0 + row;
      float4 v = make_float4(0.f,0.f,0.f,0.f);
      if (gr < n) v = x4[gr*(HDIM/4) + c4];
      short4v p;
      p.x=(short)f2bf(v.x); p.y=(short)f2bf(v.y); p.z=(short)f2bf(v.z); p.w=(short)f2bf(v.w);
      *(short4v*)(As + row*APITCH + c4*4) = p;
    }
    __syncthreads();                       // S1: As staged

    #pragma unroll 1
    for (int rt=0; rt<MTILE/16; ++rt){
      floatx4 acc[4];
      #pragma unroll
      for (int ct=0;ct<4;++ct) acc[ct] = (floatx4){0.f,0.f,0.f,0.f};
      #pragma unroll
      for (int kc=0; kc<8; ++kc){
        short8 a = *(const short8*)(As + (rt*16 + l15)*APITCH + kc*32 + quad*8);
        #pragma unroll
        for (int ct=0; ct<4; ++ct)
          acc[ct] = __builtin_amdgcn_mfma_f32_16x16x32_bf16(a, bf[kc][ct], acc[ct], 0, 0, 0);
      }
      float part[4] = {0.f,0.f,0.f,0.f};
      #pragma unroll
      for (int ct=0; ct<4; ++ct){
        #pragma unroll
        for (int r=0; r<4; ++r){
          float h = acc[ct][r] + b1v[ct];
          float z = fminf(fmaxf(2.f*h, -30.f), 30.f);
          float e = __expf(z);
          part[r] += __fdividef(e-1.f, e+1.f) * w2v[ct];
        }
      }
      #pragma unroll
      for (int off=8; off>=1; off>>=1){
        #pragma unroll
        for (int r=0;r<4;++r) part[r] += __shfl_xor(part[r], off, 64);
      }
      if (l15==0){
        #pragma unroll
        for (int r=0;r<4;++r) sp[wv][rt*16 + quad*4 + r] = part[r];
      }
    }
    __syncthreads();                       // S2: sp complete

    // per-wave: e = exp(s) for OWN 16 rows, in registers (no barrier needed:
    // sp reads here are ordered before next iter's sp writes by S1/S2).
    const int myrow = rb + l15;            // 4 redundant copies per row
    float e_own = 0.f;
    int b_own = sbat[it*MTILE + myrow];
    if (node0 + myrow < n){
      float sv = sp[0][myrow]+sp[1][myrow]+sp[2][myrow]+sp[3][myrow] + b2v;
      e_own = __expf(sv);
    }
    {
      int bfirst = __shfl(b_own, 0, 64);
      if (__all(b_own == bfirst)){
        float tot = e_own;
        #pragma unroll
        for (int off=8; off>=1; off>>=1) tot += __shfl_xor(tot, off, 64);
        if (lane==0 && bfirst >= 0) atomicAdd(&denom[bfirst], tot);
      } else if (lane < 16 && b_own >= 0){
        atomicAdd(&denom[b_own], e_own);
      }
    }

    // pooling: this wave's 16 rows, branchless fast path when segment-uniform
    {
      int rend = (int)(((n - node0) < (long long)MTILE) ? (n - node0) : (long long)MTILE);
      int whi = rb + 16 < rend ? rb + 16 : rend;
      if (rb < rend){
        int bhead = sbat[it*MTILE + rb];
        int btail = sbat[it*MTILE + whi - 1];
        if (bhead == btail && whi == rb + 16){
          if (bhead != curb){
            if (curb >= 0) FLUSH();
            curb = bhead;
            psum = make_float4(0.f,0.f,0.f,0.f);
            patt = make_float4(0.f,0.f,0.f,0.f);
            pmx  = make_float4(-INFINITY,-INFINITY,-INFINITY,-INFINITY);
          }
          #pragma unroll
          for (int r=0; r<16; ++r)
            ACCROW(node0 + rb + r, __shfl(e_own, r, 64))
        } else {
          for (int r=rb; r<whi; ++r){
            int b = sbat[it*MTILE + r];
            if (b != curb){
              if (curb >= 0) FLUSH();
              curb = b;
              psum = make_float4(0.f,0.f,0.f,0.f);
              patt = make_float4(0.f,0.f,0.f,0.f);
              pmx  = make_float4(-INFINITY,-INFINITY,-INFINITY,-INFINITY);
            }
            ACCROW(node0 + r, __shfl(e_own, r - rb, 64))
          }
        }
      }
    }
    // no barrier here: next staging only writes As; pool reads x/registers.
  }

  if (curb >= 0) FLUSH();
#undef FLUSH
#undef ACCROW
}

__global__ void k_fin(const float* __restrict__ sums, const unsigned* __restrict__ maxu,
                      const float* __restrict__ attn, const float* __restrict__ denom,
                      const int* __restrict__ segstart,
                      float* __restrict__ out, int bcount){
  int idx = blockIdx.x*256 + threadIdx.x;
  int total = bcount*3*HDIM;
  if (idx >= total) return;
  int b = idx / (3*HDIM);
  int c = idx - b*(3*HDIM);
  int cnt = segstart[b+1] - segstart[b];
  float v;
  if (c < HDIM)        v = sums[(size_t)b*HDIM + c] / fmaxf((float)cnt, 1.f);
  else if (c < 2*HDIM) v = (cnt > 0) ? fdec(maxu[(size_t)b*HDIM + (c-HDIM)]) : 0.f;
  else                 v = attn[(size_t)b*HDIM + (c-2*HDIM)] / fmaxf(denom[b], 1e-30f);
  out[idx] = v;
}

extern "C" void kernel_launch(void* const* d_in, const int* in_sizes, int n_in,
                              void* d_out, int out_size, void* d_ws, size_t ws_size,
                              hipStream_t stream){
  const float* x   = (const float*)d_in[0];
  const int* batch = (const int*)d_in[1];
  const float* W1  = (const float*)d_in[2];
  const float* b1  = (const float*)d_in[3];
  const float* W2  = (const float*)d_in[4];
  const float* b2  = (const float*)d_in[5];
  float* out = (float*)d_out;
  const int n = in_sizes[1];
  const int B = out_size / (3*HDIM);

  char* w = (char*)d_ws;
  unsigned short* W1T = (unsigned short*)w;
  size_t off = (size_t)HDIM*HDIM*2;
  int* segstart = (int*)(w + off);
  off += (size_t)((B+4)&~3)*4;
  float* stats = (float*)(w + off);
  float* denom  = stats;                                   // [B]
  float* sums   = stats + B;                               // [B,H]
  unsigned* maxu = (unsigned*)(stats + B + (size_t)B*HDIM);// [B,H]
  float* attn   = stats + B + 2*(size_t)B*HDIM;            // [B,H]
  int zerowords = B + 3*B*HDIM;

  int ZB  = (zerowords + 255)/256;
  int PB  = HDIM;
  int NBB = (n + 255)/256;
  hipLaunchKernelGGL(k_pre, dim3(ZB + PB + NBB), dim3(256), 0, stream,
                     W1, W1T, batch, segstart, stats, zerowords, n, B, ZB, PB);
  hipLaunchKernelGGL(k_main, dim3((n + MTILE*NITER - 1)/(MTILE*NITER)), dim3(256), 0, stream,
                     x, W1T, b1, W2, b2, batch, denom, sums, maxu, attn, n);
  hipLaunchKernelGGL(k_fin, dim3((out_size + 255)/256), dim3(256), 0, stream,
                     sums, maxu, attn, denom, segstart, out, B);
}

// Round 3
// 906.646 us; speedup vs baseline: 1.1867x; 1.1650x over previous
//
#include <hip/hip_runtime.h>

#define HDIM 256
#define MTILE 64
#define NITER 4          // row-tiles per scores block (256 rows/block)
#define APITCH 264       // 256 + 8 pad (shorts)
#define PROWS 256
#define CHUNK 16

typedef __attribute__((ext_vector_type(8))) short short8;
typedef __attribute__((ext_vector_type(4))) short short4v;
typedef __attribute__((ext_vector_type(4))) float floatx4;

__device__ __forceinline__ unsigned short f2bf(float f){
  unsigned u = __float_as_uint(f);
  u += 0x7FFFu + ((u>>16)&1u);
  return (unsigned short)(u>>16);
}
__device__ __forceinline__ unsigned fkey(float f){
  unsigned u = __float_as_uint(f);
  return u ^ ((unsigned)((int)u>>31) | 0x80000000u);
}
__device__ __forceinline__ float fdec(unsigned u){
  unsigned b = (u & 0x80000000u) ? (u & 0x7FFFFFFFu) : ~u;
  return __uint_as_float(b);
}

// fused pre-pass: [0,ZB) zero stats | [ZB,ZB+PB) W1->bf16 transpose | rest: segment bounds
__global__ void k_pre(const float* __restrict__ W1, unsigned short* __restrict__ W1T,
                      const int* __restrict__ batch, int* __restrict__ segstart,
                      float* __restrict__ zbuf, int zerowords, int n, int B,
                      int ZB, int PB){
  const int bid = blockIdx.x, t = threadIdx.x;
  if (bid < ZB){
    int i = bid*256 + t;
    if (i < zerowords) zbuf[i] = 0.f;
  } else if (bid < ZB + PB){
    int col = bid - ZB;
    W1T[col*HDIM + t] = f2bf(W1[t*HDIM + col]);
  } else {
    int i = (bid - ZB - PB)*256 + t;
    if (i >= n) return;
    int b = batch[i];
    int prev = (i == 0) ? -1 : batch[i-1];
    if (prev != b) for (int q = prev+1; q <= b; ++q) segstart[q] = i;
    if (i == n-1) for (int q = b+1; q <= B; ++q) segstart[q] = n;
  }
}

// e = exp(tanh(x@W1+b1)@W2+b2) via bf16 MFMA; also accumulates segment denoms.
// No max-subtraction: |s| <= sum|W2| <= 16, exp is fp32-safe, and the segmax
// factor cancels in attn/denom (validated: absmax 9.8e-4 in prior rounds).
__launch_bounds__(256)
__global__ void k_scores(const float* __restrict__ x,
                         const unsigned short* __restrict__ w1t,
                         const float* __restrict__ b1,
                         const float* __restrict__ w2,
                         const float* __restrict__ b2,
                         const int* __restrict__ batch,
                         float* __restrict__ eo,
                         float* __restrict__ denom, int n)
{
  __shared__ unsigned short As[MTILE*APITCH];
  __shared__ float sp[4][MTILE];
  const int t = threadIdx.x;
  const int wv = t>>6;
  const int lane = t&63;
  const int l15 = lane&15;
  const int quad = lane>>4;
  const long long base = (long long)blockIdx.x * (MTILE*NITER);

  // B fragments: wave wv owns cols [wv*64, wv*64+64), all K in registers
  short8 bf[8][4];
  float b1v[4], w2v[4];
  const int cb = wv*64;
  #pragma unroll
  for (int ct=0; ct<4; ++ct){
    int col = cb + ct*16 + l15;
    b1v[ct] = b1[col];
    w2v[ct] = w2[col];
    #pragma unroll
    for (int kc=0; kc<8; ++kc)
      bf[kc][ct] = *(const short8*)(w1t + (size_t)col*HDIM + kc*32 + quad*8);
  }
  const float b2v = b2[0];

  const float4* x4 = (const float4*)x;
  for (int it = 0; it < NITER; ++it){
    const long long node0 = base + (long long)it*MTILE;
    if (node0 >= n) break;

    // stage A tile (64 rows x 256 k) fp32->bf16 into LDS, coalesced
    #pragma unroll
    for (int j=0; j<MTILE/4; ++j){
      int f = j*256 + t;
      int row = f>>6, c4 = f&63;
      long long gr = node0 + row;
      float4 v = make_float4(0.f,0.f,0.f,0.f);
      if (gr < n) v = x4[gr*(HDIM/4) + c4];
      short4v p;
      p.x=(short)f2bf(v.x); p.y=(short)f2bf(v.y); p.z=(short)f2bf(v.z); p.w=(short)f2bf(v.w);
      *(short4v*)(As + row*APITCH + c4*4) = p;
    }
    __syncthreads();                       // S1: As staged

    #pragma unroll 1
    for (int rt=0; rt<MTILE/16; ++rt){
      floatx4 acc[4];
      #pragma unroll
      for (int ct=0;ct<4;++ct) acc[ct] = (floatx4){0.f,0.f,0.f,0.f};
      #pragma unroll
      for (int kc=0; kc<8; ++kc){
        short8 a = *(const short8*)(As + (rt*16 + l15)*APITCH + kc*32 + quad*8);
        #pragma unroll
        for (int ct=0; ct<4; ++ct)
          acc[ct] = __builtin_amdgcn_mfma_f32_16x16x32_bf16(a, bf[kc][ct], acc[ct], 0, 0, 0);
      }
      float part[4] = {0.f,0.f,0.f,0.f};
      #pragma unroll
      for (int ct=0; ct<4; ++ct){
        #pragma unroll
        for (int r=0; r<4; ++r){
          float h = acc[ct][r] + b1v[ct];
          float z = fminf(fmaxf(2.f*h, -30.f), 30.f);
          float e = __expf(z);
          part[r] += __fdividef(e-1.f, e+1.f) * w2v[ct];
        }
      }
      #pragma unroll
      for (int off=8; off>=1; off>>=1){
        #pragma unroll
        for (int r=0;r<4;++r) part[r] += __shfl_xor(part[r], off, 64);
      }
      if (l15==0){
        #pragma unroll
        for (int r=0;r<4;++r) sp[wv][rt*16 + quad*4 + r] = part[r];
      }
    }
    __syncthreads();                       // S2: sp complete

    // wave 0: s -> e = exp(s), write out, reduce segment denominators.
    // (sp rewrite next iter is ordered by the post-staging barrier S1.)
    if (t < MTILE){
      long long gr = node0 + t;
      float e = 0.f; int b = -1;
      if (gr < n){
        float sv = sp[0][t]+sp[1][t]+sp[2][t]+sp[3][t] + b2v;
        e = __expf(sv);
        eo[gr] = e;
        b = batch[gr];
      }
      int b0 = __shfl(b, 0, 64);
      if (__all(b == b0)){                 // whole 64-row tile in one segment (common)
        float tot = e;
        #pragma unroll
        for (int off=32; off>=1; off>>=1) tot += __shfl_xor(tot, off, 64);
        if (lane==0 && b0 >= 0) atomicAdd(&denom[b0], tot);
      } else if (b >= 0){
        atomicAdd(&denom[b], e);
      }
    }
  }
}

// pooling: thread t owns column t; 16-row unrolled fast path (proven structure).
// attn accumulates x*e unnormalized; k_fin divides by denom.
__launch_bounds__(256)
__global__ void k_pool(const float* __restrict__ x, const int* __restrict__ batch,
                       const float* __restrict__ e,
                       float* __restrict__ sums, unsigned* __restrict__ maxu,
                       float* __restrict__ attn, int n){
  const int t = threadIdx.x;
  long long r0 = (long long)blockIdx.x * PROWS;
  if (r0 >= n) return;
  long long r1 = r0 + PROWS; if (r1 > n) r1 = n;
  int curb = batch[r0];
  float sum=0.f, att=0.f, mx=-INFINITY;
  long long i = r0;
  while (i < r1){
    if (i + CHUNK <= r1 && batch[i + CHUNK - 1] == curb){
      float v[CHUNK], w[CHUNK];
      #pragma unroll
      for (int k=0;k<CHUNK;++k) v[k] = x[(i+k)*HDIM + t];
      #pragma unroll
      for (int k=0;k<CHUNK;++k) w[k] = e[i+k];
      #pragma unroll
      for (int k=0;k<CHUNK;++k){
        sum += v[k];
        att = fmaf(v[k], w[k], att);
        mx = fmaxf(mx, v[k]);
      }
      i += CHUNK;
    } else {
      int b = batch[i];
      if (b != curb){
        atomicAdd(&sums[(size_t)curb*HDIM + t], sum);
        atomicAdd(&attn[(size_t)curb*HDIM + t], att);
        atomicMax(&maxu[(size_t)curb*HDIM + t], fkey(mx));
        curb=b; sum=0.f; att=0.f; mx=-INFINITY;
      }
      float v = x[i*HDIM + t];
      sum += v; att = fmaf(v, e[i], att); mx = fmaxf(mx, v);
      ++i;
    }
  }
  atomicAdd(&sums[(size_t)curb*HDIM + t], sum);
  atomicAdd(&attn[(size_t)curb*HDIM + t], att);
  atomicMax(&maxu[(size_t)curb*HDIM + t], fkey(mx));
}

__global__ void k_fin(const float* __restrict__ sums, const unsigned* __restrict__ maxu,
                      const float* __restrict__ attn, const float* __restrict__ denom,
                      const int* __restrict__ segstart,
                      float* __restrict__ out, int bcount){
  int idx = blockIdx.x*256 + threadIdx.x;
  int total = bcount*3*HDIM;
  if (idx >= total) return;
  int b = idx / (3*HDIM);
  int c = idx - b*(3*HDIM);
  int cnt = segstart[b+1] - segstart[b];
  float v;
  if (c < HDIM)        v = sums[(size_t)b*HDIM + c] / fmaxf((float)cnt, 1.f);
  else if (c < 2*HDIM) v = (cnt > 0) ? fdec(maxu[(size_t)b*HDIM + (c-HDIM)]) : 0.f;
  else                 v = attn[(size_t)b*HDIM + (c-2*HDIM)] / fmaxf(denom[b], 1e-30f);
  out[idx] = v;
}

extern "C" void kernel_launch(void* const* d_in, const int* in_sizes, int n_in,
                              void* d_out, int out_size, void* d_ws, size_t ws_size,
                              hipStream_t stream){
  const float* x   = (const float*)d_in[0];
  const int* batch = (const int*)d_in[1];
  const float* W1  = (const float*)d_in[2];
  const float* b1  = (const float*)d_in[3];
  const float* W2  = (const float*)d_in[4];
  const float* b2  = (const float*)d_in[5];
  float* out = (float*)d_out;
  const int n = in_sizes[1];
  const int B = out_size / (3*HDIM);

  char* w = (char*)d_ws;
  unsigned short* W1T = (unsigned short*)w;
  size_t off = (size_t)HDIM*HDIM*2;
  float* e = (float*)(w + off);
  off += (size_t)((n+3)&~3)*4;
  int* segstart = (int*)(w + off);
  off += (size_t)((B+4)&~3)*4;
  float* stats = (float*)(w + off);
  float* denom  = stats;                                   // [B]
  float* sums   = stats + B;                               // [B,H]
  unsigned* maxu = (unsigned*)(stats + B + (size_t)B*HDIM);// [B,H]
  float* attn   = stats + B + 2*(size_t)B*HDIM;            // [B,H]
  int zerowords = B + 3*B*HDIM;

  int ZB  = (zerowords + 255)/256;
  int PB  = HDIM;
  int NBB = (n + 255)/256;
  hipLaunchKernelGGL(k_pre, dim3(ZB + PB + NBB), dim3(256), 0, stream,
                     W1, W1T, batch, segstart, stats, zerowords, n, B, ZB, PB);
  hipLaunchKernelGGL(k_scores, dim3((n + MTILE*NITER - 1)/(MTILE*NITER)), dim3(256), 0, stream,
                     x, W1T, b1, W2, b2, batch, e, denom, n);
  hipLaunchKernelGGL(k_pool, dim3((n+PROWS-1)/PROWS), dim3(256), 0, stream,
                     x, batch, e, sums, maxu, attn, n);
  hipLaunchKernelGGL(k_fin, dim3((out_size+255)/256), dim3(256), 0, stream,
                     sums, maxu, attn, denom, segstart, out, B);
}